// Round 1
// baseline (309.508 us; speedup 1.0000x reference)
//
#include <hip/hip_runtime.h>
#include <math.h>

#define D 256
#define NBATCH 8
#define T 4096
#define M (NBATCH * T)     // 32768
#define LC 64              // chunk length
#define NC (T / LC)        // 64 chunks

// ---------------- parameter precompute ----------------
__global__ void params_kernel(const float* __restrict__ nu_log,
                              const float* __restrict__ theta_log,
                              const float* __restrict__ gamma_log,
                              float* __restrict__ Lr, float* __restrict__ Li,
                              float* __restrict__ g) {
    int d = threadIdx.x;
    float lmod = expf(-expf(nu_log[d]));
    float th = expf(theta_log[d]);
    Lr[d] = lmod * cosf(th);
    Li[d] = lmod * sinf(th);
    g[d] = expf(gamma_log[d]);
}

// ---------------- projection GEMM: U = (x @ B_re^T) * g,  V = (x @ B_im^T) * g
// x[M][256] row-major, W[d][k] row-major. Tile 64x64, BK=32, 256 thr, 4x4/thread.
__global__ __launch_bounds__(256) void proj_gemm(const float* __restrict__ x,
                                                 const float* __restrict__ Wre,
                                                 const float* __restrict__ Wim,
                                                 const float* __restrict__ g,
                                                 float* __restrict__ U,
                                                 float* __restrict__ V) {
    __shared__ float As[64][33];
    __shared__ __align__(16) float Bre[32][64];
    __shared__ __align__(16) float Bim[32][64];
    int tid = threadIdx.x;
    int m0 = blockIdx.x * 64;
    int n0 = blockIdx.y * 64;
    int tx = tid & 15, ty = tid >> 4;
    int tx4 = tx * 4, ty4 = ty * 4;
    float accU[4][4] = {{0.f}}, accV[4][4] = {{0.f}};

    for (int k0 = 0; k0 < 256; k0 += 32) {
        __syncthreads();
#pragma unroll
        for (int i = 0; i < 2; i++) {
            int idx = tid + i * 256;
            int r = idx >> 3, c4 = (idx & 7) * 4;
            float4 va = *(const float4*)(x + (size_t)(m0 + r) * 256 + k0 + c4);
            As[r][c4 + 0] = va.x; As[r][c4 + 1] = va.y;
            As[r][c4 + 2] = va.z; As[r][c4 + 3] = va.w;
            float4 vr = *(const float4*)(Wre + (size_t)(n0 + r) * 256 + k0 + c4);
            float4 vi = *(const float4*)(Wim + (size_t)(n0 + r) * 256 + k0 + c4);
            Bre[c4 + 0][r] = vr.x; Bre[c4 + 1][r] = vr.y;
            Bre[c4 + 2][r] = vr.z; Bre[c4 + 3][r] = vr.w;
            Bim[c4 + 0][r] = vi.x; Bim[c4 + 1][r] = vi.y;
            Bim[c4 + 2][r] = vi.z; Bim[c4 + 3][r] = vi.w;
        }
        __syncthreads();
#pragma unroll
        for (int kk = 0; kk < 32; kk++) {
            float a[4], wr[4], wi[4];
#pragma unroll
            for (int mi = 0; mi < 4; mi++) a[mi] = As[ty4 + mi][kk];
            *(float4*)wr = *(const float4*)&Bre[kk][tx4];
            *(float4*)wi = *(const float4*)&Bim[kk][tx4];
#pragma unroll
            for (int mi = 0; mi < 4; mi++)
#pragma unroll
                for (int ni = 0; ni < 4; ni++) {
                    accU[mi][ni] += a[mi] * wr[ni];
                    accV[mi][ni] += a[mi] * wi[ni];
                }
        }
    }
    float4 gv = *(const float4*)(g + n0 + tx4);
#pragma unroll
    for (int mi = 0; mi < 4; mi++) {
        size_t row = (size_t)(m0 + ty4 + mi) * 256 + n0 + tx4;
        float4 uo = make_float4(accU[mi][0] * gv.x, accU[mi][1] * gv.y,
                                accU[mi][2] * gv.z, accU[mi][3] * gv.w);
        float4 vo = make_float4(accV[mi][0] * gv.x, accV[mi][1] * gv.y,
                                accV[mi][2] * gv.z, accV[mi][3] * gv.w);
        *(float4*)(U + row) = uo;
        *(float4*)(V + row) = vo;
    }
}

// ---------------- phase 1: local (within-chunk) scan, in place; emit chunk end state
__global__ __launch_bounds__(256) void scan_local(float* __restrict__ U, float* __restrict__ V,
                                                  const float* __restrict__ Lr,
                                                  const float* __restrict__ Li,
                                                  float* __restrict__ cre, float* __restrict__ cim) {
    int d = threadIdx.x;
    int bc = blockIdx.x;
    int b = bc / NC, c = bc % NC;
    float lr = Lr[d], li = Li[d];
    float hr = 0.f, hi = 0.f;
    size_t base = ((size_t)b * T + (size_t)c * LC) * D + d;
    for (int t = 0; t < LC; t++) {
        float u = U[base + (size_t)t * D];
        float v = V[base + (size_t)t * D];
        float nr = fmaf(lr, hr, fmaf(-li, hi, u));
        float ni = fmaf(lr, hi, fmaf(li, hr, v));
        hr = nr; hi = ni;
        U[base + (size_t)t * D] = hr;
        V[base + (size_t)t * D] = hi;
    }
    cre[(size_t)bc * D + d] = hr;
    cim[(size_t)bc * D + d] = hi;
}

// ---------------- phase 2: scan across chunk carries (per batch, per channel)
__global__ __launch_bounds__(256) void scan_carry(float* __restrict__ cre, float* __restrict__ cim,
                                                  const float* __restrict__ Lr,
                                                  const float* __restrict__ Li) {
    int d = threadIdx.x;
    int b = blockIdx.x;
    float lr = Lr[d], li = Li[d];
    // A = L^LC
    float ar = 1.f, ai = 0.f;
    for (int i = 0; i < LC; i++) {
        float nr = ar * lr - ai * li;
        float ni = ar * li + ai * lr;
        ar = nr; ai = ni;
    }
    float hr = 0.f, hi = 0.f;
    for (int c = 0; c < NC; c++) {
        size_t idx = ((size_t)b * NC + c) * D + d;
        float xr = cre[idx], xi = cim[idx];
        cre[idx] = hr;  // exclusive: carry-in for chunk c
        cim[idx] = hi;
        float nr = fmaf(ar, hr, fmaf(-ai, hi, xr));
        float ni = fmaf(ar, hi, fmaf(ai, hr, xi));
        hr = nr; hi = ni;
    }
}

// ---------------- phase 3: add carry contribution L^{t+1} * carry_in
__global__ __launch_bounds__(256) void apply_carry(float* __restrict__ U, float* __restrict__ V,
                                                   const float* __restrict__ Lr,
                                                   const float* __restrict__ Li,
                                                   const float* __restrict__ cre,
                                                   const float* __restrict__ cim) {
    int d = threadIdx.x;
    int bc = blockIdx.x;
    int b = bc / NC, c = bc % NC;
    if (c == 0) return;  // carry-in is zero
    float lr = Lr[d], li = Li[d];
    float hr = cre[(size_t)bc * D + d];
    float hi = cim[(size_t)bc * D + d];
    size_t base = ((size_t)b * T + (size_t)c * LC) * D + d;
    for (int t = 0; t < LC; t++) {
        float nr = lr * hr - li * hi;   // h = L * h  (value L^{t+1} * carry)
        float ni = lr * hi + li * hr;
        hr = nr; hi = ni;
        U[base + (size_t)t * D] += hr;
        V[base + (size_t)t * D] += hi;
    }
}

// ---------------- output GEMM: out = U @ Cre^T - V @ Cim^T
__global__ __launch_bounds__(256) void out_gemm(const float* __restrict__ U,
                                                const float* __restrict__ V,
                                                const float* __restrict__ Cre,
                                                const float* __restrict__ Cim,
                                                float* __restrict__ out) {
    __shared__ float Us[64][33];
    __shared__ float Vs[64][33];
    __shared__ __align__(16) float Br[32][64];
    __shared__ __align__(16) float Bi[32][64];
    int tid = threadIdx.x;
    int m0 = blockIdx.x * 64;
    int n0 = blockIdx.y * 64;
    int tx = tid & 15, ty = tid >> 4;
    int tx4 = tx * 4, ty4 = ty * 4;
    float acc[4][4] = {{0.f}};

    for (int k0 = 0; k0 < 256; k0 += 32) {
        __syncthreads();
#pragma unroll
        for (int i = 0; i < 2; i++) {
            int idx = tid + i * 256;
            int r = idx >> 3, c4 = (idx & 7) * 4;
            float4 vu = *(const float4*)(U + (size_t)(m0 + r) * 256 + k0 + c4);
            float4 vv = *(const float4*)(V + (size_t)(m0 + r) * 256 + k0 + c4);
            Us[r][c4 + 0] = vu.x; Us[r][c4 + 1] = vu.y;
            Us[r][c4 + 2] = vu.z; Us[r][c4 + 3] = vu.w;
            Vs[r][c4 + 0] = vv.x; Vs[r][c4 + 1] = vv.y;
            Vs[r][c4 + 2] = vv.z; Vs[r][c4 + 3] = vv.w;
            float4 vr = *(const float4*)(Cre + (size_t)(n0 + r) * 256 + k0 + c4);
            float4 vi = *(const float4*)(Cim + (size_t)(n0 + r) * 256 + k0 + c4);
            Br[c4 + 0][r] = vr.x; Br[c4 + 1][r] = vr.y;
            Br[c4 + 2][r] = vr.z; Br[c4 + 3][r] = vr.w;
            Bi[c4 + 0][r] = vi.x; Bi[c4 + 1][r] = vi.y;
            Bi[c4 + 2][r] = vi.z; Bi[c4 + 3][r] = vi.w;
        }
        __syncthreads();
#pragma unroll
        for (int kk = 0; kk < 32; kk++) {
            float u[4], v[4], cr[4], ci[4];
#pragma unroll
            for (int mi = 0; mi < 4; mi++) {
                u[mi] = Us[ty4 + mi][kk];
                v[mi] = Vs[ty4 + mi][kk];
            }
            *(float4*)cr = *(const float4*)&Br[kk][tx4];
            *(float4*)ci = *(const float4*)&Bi[kk][tx4];
#pragma unroll
            for (int mi = 0; mi < 4; mi++)
#pragma unroll
                for (int ni = 0; ni < 4; ni++) {
                    acc[mi][ni] += u[mi] * cr[ni];
                    acc[mi][ni] -= v[mi] * ci[ni];
                }
        }
    }
#pragma unroll
    for (int mi = 0; mi < 4; mi++) {
        size_t row = (size_t)(m0 + ty4 + mi) * 256 + n0 + tx4;
        *(float4*)(out + row) = make_float4(acc[mi][0], acc[mi][1], acc[mi][2], acc[mi][3]);
    }
}

extern "C" void kernel_launch(void* const* d_in, const int* in_sizes, int n_in,
                              void* d_out, int out_size, void* d_ws, size_t ws_size,
                              hipStream_t stream) {
    const float* x         = (const float*)d_in[0];
    const float* nu_log    = (const float*)d_in[1];
    const float* theta_log = (const float*)d_in[2];
    const float* gamma_log = (const float*)d_in[3];
    const float* B_re      = (const float*)d_in[4];
    const float* B_im      = (const float*)d_in[5];
    const float* C_re      = (const float*)d_in[6];
    const float* C_im      = (const float*)d_in[7];
    float* out = (float*)d_out;

    float* U   = (float*)d_ws;                       // M*D floats (32 MB)
    float* V   = U + (size_t)M * D;                  // M*D floats (32 MB)
    float* cre = V + (size_t)M * D;                  // NBATCH*NC*D
    float* cim = cre + (size_t)NBATCH * NC * D;
    float* Lr  = cim + (size_t)NBATCH * NC * D;
    float* Li  = Lr + D;
    float* g   = Li + D;

    params_kernel<<<1, 256, 0, stream>>>(nu_log, theta_log, gamma_log, Lr, Li, g);
    proj_gemm<<<dim3(M / 64, D / 64), 256, 0, stream>>>(x, B_re, B_im, g, U, V);
    scan_local<<<NBATCH * NC, 256, 0, stream>>>(U, V, Lr, Li, cre, cim);
    scan_carry<<<NBATCH, 256, 0, stream>>>(cre, cim, Lr, Li);
    apply_carry<<<NBATCH * NC, 256, 0, stream>>>(U, V, Lr, Li, cre, cim);
    out_gemm<<<dim3(M / 64, D / 64), 256, 0, stream>>>(U, V, C_re, C_im, out);
}

// Round 2
// 81.533 us; speedup vs baseline: 3.7961x; 3.7961x over previous
//
#include <hip/hip_runtime.h>
#include <math.h>

#define D 256
#define NBATCH 8
#define T 4096
#define M (NBATCH * T)     // 32768
#define LC 64              // chunk length
#define NC (T / LC)        // 64 chunks

typedef __attribute__((ext_vector_type(8))) short bf16x8;
typedef __attribute__((ext_vector_type(4))) float f32x4;

__device__ __forceinline__ unsigned short f2bf(float f) {
    unsigned int u = __float_as_uint(f);
    u += 0x7fff + ((u >> 16) & 1);          // round-to-nearest-even
    return (unsigned short)(u >> 16);
}
__device__ __forceinline__ float bf2f(unsigned short s) {
    return __uint_as_float(((unsigned int)s) << 16);
}

__device__ __forceinline__ void gl_lds16(const unsigned short* g, unsigned short* l) {
    __builtin_amdgcn_global_load_lds(
        (const __attribute__((address_space(1))) unsigned int*)g,
        (__attribute__((address_space(3))) unsigned int*)l, 16, 0, 0);
}

// ---------------- params: L diagonal ----------------
__global__ void prep_params(const float* __restrict__ nu_log,
                            const float* __restrict__ theta_log,
                            float* __restrict__ Lr, float* __restrict__ Li) {
    int d = threadIdx.x;
    float lmod = expf(-expf(nu_log[d]));
    float th = expf(theta_log[d]);
    Lr[d] = lmod * cosf(th);
    Li[d] = lmod * sinf(th);
}

// ---------------- weights: W2 = [Bre*g ; Bim*g] (512x256), W3 = [Cre | -Cim] (256x512)
__global__ __launch_bounds__(256) void prep_w(const float* __restrict__ Bre,
                                              const float* __restrict__ Bim,
                                              const float* __restrict__ gamma_log,
                                              const float* __restrict__ Cre,
                                              const float* __restrict__ Cim,
                                              unsigned short* __restrict__ W2,
                                              unsigned short* __restrict__ W3) {
    int n = blockIdx.x, k = threadIdx.x;
    if (n < 512) {
        int r = n & 255;
        float g = expf(gamma_log[r]);
        const float* src = (n < 256) ? Bre : Bim;
        W2[(size_t)n * 256 + k] = f2bf(src[(size_t)r * 256 + k] * g);
    } else {
        int r = n - 512;
        W3[(size_t)r * 512 + k]       = f2bf(Cre[(size_t)r * 256 + k]);
        W3[(size_t)r * 512 + 256 + k] = f2bf(-Cim[(size_t)r * 256 + k]);
    }
}

// ---------------- x -> bf16 ----------------
__global__ __launch_bounds__(256) void conv_x(const float* __restrict__ x,
                                              unsigned short* __restrict__ xb) {
    const size_t i = (size_t)blockIdx.x * 256 + threadIdx.x;   // 8 elems/thread
    const float4 v0 = ((const float4*)x)[i * 2];
    const float4 v1 = ((const float4*)x)[i * 2 + 1];
    union { unsigned short s[8]; uint4 u4; } o;
    o.s[0] = f2bf(v0.x); o.s[1] = f2bf(v0.y); o.s[2] = f2bf(v0.z); o.s[3] = f2bf(v0.w);
    o.s[4] = f2bf(v1.x); o.s[5] = f2bf(v1.y); o.s[6] = f2bf(v1.z); o.s[7] = f2bf(v1.w);
    ((uint4*)xb)[i] = o.u4;
}

// ---------------- bf16 MFMA GEMM, B^T weights: out[m][n] = sum_k A[m][k]*W[n][k]
// 128x128 tile, BK=32, 4 waves (2x2 of 64x64), 16x16x32 mfma, global_load_lds x16.
// EPI==0: N=512, split cols 0-255 -> oU bf16, 256-511 -> oV bf16 (proj)
// EPI==1: N=256, write fp32 to oF (output projection)
template<int K, int EPI>
__global__ __launch_bounds__(256) void gemm_bt(const unsigned short* __restrict__ A,
                                               const unsigned short* __restrict__ W,
                                               unsigned short* __restrict__ oU,
                                               unsigned short* __restrict__ oV,
                                               float* __restrict__ oF) {
    __shared__ __align__(16) unsigned short As[128 * 32];
    __shared__ __align__(16) unsigned short Bs[128 * 32];
    const int tid  = threadIdx.x;
    const int lane = tid & 63;
    const int wid  = tid >> 6;
    const int m0 = blockIdx.x * 128;
    const int n0 = blockIdx.y * 128;
    const int wr = wid >> 1, wc = wid & 1;

    f32x4 acc[4][4];
#pragma unroll
    for (int i = 0; i < 4; ++i)
#pragma unroll
        for (int j = 0; j < 4; ++j) acc[i][j] = (f32x4){0.f, 0.f, 0.f, 0.f};

    // staging: wave w stages rows [w*32, w*32+32) of each 128x32 tile (2 x 1024B chunks)
    const int sr = lane >> 2;
    const int sc = (lane & 3) * 8;
    const unsigned short* gA0 = A + (size_t)(m0 + wid * 32 + sr) * K + sc;
    const unsigned short* gA1 = gA0 + (size_t)16 * K;
    const unsigned short* gW0 = W + (size_t)(n0 + wid * 32 + sr) * K + sc;
    const unsigned short* gW1 = gW0 + (size_t)16 * K;
    unsigned short* lA0 = As + wid * 1024;
    unsigned short* lA1 = lA0 + 512;
    unsigned short* lB0 = Bs + wid * 1024;
    unsigned short* lB1 = lB0 + 512;

    const int ar = lane & 15;          // fragment row/col within 16
    const int ak = (lane >> 4) * 8;    // k-offset (8 bf16)

    for (int k0 = 0; k0 < K; k0 += 32) {
        gl_lds16(gA0 + k0, lA0);
        gl_lds16(gA1 + k0, lA1);
        gl_lds16(gW0 + k0, lB0);
        gl_lds16(gW1 + k0, lB1);
        __syncthreads();               // drains vmcnt -> tiles visible
        bf16x8 a[4], b[4];
#pragma unroll
        for (int mi = 0; mi < 4; ++mi)
            a[mi] = *(const bf16x8*)(As + (wr * 64 + mi * 16 + ar) * 32 + ak);
#pragma unroll
        for (int ni = 0; ni < 4; ++ni)
            b[ni] = *(const bf16x8*)(Bs + (wc * 64 + ni * 16 + ar) * 32 + ak);
#pragma unroll
        for (int mi = 0; mi < 4; ++mi)
#pragma unroll
            for (int ni = 0; ni < 4; ++ni)
                acc[mi][ni] = __builtin_amdgcn_mfma_f32_16x16x32_bf16(a[mi], b[ni], acc[mi][ni], 0, 0, 0);
        __syncthreads();               // before next-iter overwrite
    }

    // C/D layout (16x16x32): col = lane&15, row = (lane>>4)*4 + j
    const int crow = (lane >> 4) * 4;
    const int ccol = lane & 15;
    if constexpr (EPI == 0) {
        unsigned short* base = (n0 < 256) ? oU : oV;
        const int nb = (n0 < 256) ? n0 : (n0 - 256);
#pragma unroll
        for (int mi = 0; mi < 4; ++mi)
#pragma unroll
            for (int ni = 0; ni < 4; ++ni) {
                const int r = m0 + wr * 64 + mi * 16 + crow;
                const int c = nb + wc * 64 + ni * 16 + ccol;
#pragma unroll
                for (int j = 0; j < 4; ++j)
                    base[(size_t)(r + j) * 256 + c] = f2bf(acc[mi][ni][j]);
            }
    } else {
#pragma unroll
        for (int mi = 0; mi < 4; ++mi)
#pragma unroll
            for (int ni = 0; ni < 4; ++ni) {
                const int r = m0 + wr * 64 + mi * 16 + crow;
                const int c = n0 + wc * 64 + ni * 16 + ccol;
#pragma unroll
                for (int j = 0; j < 4; ++j)
                    oF[(size_t)(r + j) * 256 + c] = acc[mi][ni][j];
            }
    }
}

// ---------------- scan pass A: chunk-local end states (read-only)
__global__ __launch_bounds__(256) void scan_ends(const unsigned short* __restrict__ Ub,
                                                 const unsigned short* __restrict__ Vb,
                                                 const float* __restrict__ Lr,
                                                 const float* __restrict__ Li,
                                                 float* __restrict__ cre, float* __restrict__ cim) {
    int d = threadIdx.x;
    int bc = blockIdx.x;
    float lr = Lr[d], li = Li[d];
    float hr = 0.f, hi = 0.f;
    size_t base = (size_t)bc * LC * 256 + d;
    for (int t = 0; t < LC; t++) {
        float u = bf2f(Ub[base + (size_t)t * 256]);
        float v = bf2f(Vb[base + (size_t)t * 256]);
        float nr = fmaf(lr, hr, fmaf(-li, hi, u));
        float ni = fmaf(lr, hi, fmaf(li, hr, v));
        hr = nr; hi = ni;
    }
    cre[(size_t)bc * 256 + d] = hr;
    cim[(size_t)bc * 256 + d] = hi;
}

// ---------------- scan pass B: carries across chunks (exclusive), A = L^LC
__global__ __launch_bounds__(256) void scan_carry(float* __restrict__ cre, float* __restrict__ cim,
                                                  const float* __restrict__ Lr,
                                                  const float* __restrict__ Li) {
    int d = threadIdx.x;
    int b = blockIdx.x;
    float lr = Lr[d], li = Li[d];
    float ar = 1.f, ai = 0.f;
    for (int i = 0; i < LC; i++) {
        float nr = ar * lr - ai * li;
        float ni = ar * li + ai * lr;
        ar = nr; ai = ni;
    }
    float hr = 0.f, hi = 0.f;
    for (int c = 0; c < NC; c++) {
        size_t idx = ((size_t)b * NC + c) * 256 + d;
        float xr = cre[idx], xi = cim[idx];
        cre[idx] = hr;
        cim[idx] = hi;
        float nr = fmaf(ar, hr, fmaf(-ai, hi, xr));
        float ni = fmaf(ar, hi, fmaf(ai, hr, xi));
        hr = nr; hi = ni;
    }
}

// ---------------- scan pass C: full scan with carry-in, emit H = [hr | hi] bf16 (M x 512)
__global__ __launch_bounds__(256) void scan_apply(const unsigned short* __restrict__ Ub,
                                                  const unsigned short* __restrict__ Vb,
                                                  const float* __restrict__ Lr,
                                                  const float* __restrict__ Li,
                                                  const float* __restrict__ cre,
                                                  const float* __restrict__ cim,
                                                  unsigned short* __restrict__ H) {
    int d = threadIdx.x;
    int bc = blockIdx.x;
    float lr = Lr[d], li = Li[d];
    float hr = cre[(size_t)bc * 256 + d];
    float hi = cim[(size_t)bc * 256 + d];
    size_t base  = (size_t)bc * LC * 256 + d;
    size_t hbase = (size_t)bc * LC * 512 + d;
    for (int t = 0; t < LC; t++) {
        float u = bf2f(Ub[base + (size_t)t * 256]);
        float v = bf2f(Vb[base + (size_t)t * 256]);
        float nr = fmaf(lr, hr, fmaf(-li, hi, u));
        float ni = fmaf(lr, hi, fmaf(li, hr, v));
        hr = nr; hi = ni;
        H[hbase + (size_t)t * 512]       = f2bf(hr);
        H[hbase + (size_t)t * 512 + 256] = f2bf(hi);
    }
}

extern "C" void kernel_launch(void* const* d_in, const int* in_sizes, int n_in,
                              void* d_out, int out_size, void* d_ws, size_t ws_size,
                              hipStream_t stream) {
    const float* x         = (const float*)d_in[0];
    const float* nu_log    = (const float*)d_in[1];
    const float* theta_log = (const float*)d_in[2];
    const float* gamma_log = (const float*)d_in[3];
    const float* B_re      = (const float*)d_in[4];
    const float* B_im      = (const float*)d_in[5];
    const float* C_re      = (const float*)d_in[6];
    const float* C_im      = (const float*)d_in[7];
    float* out = (float*)d_out;

    // workspace layout (<= ~65.6 MB):
    //   Ub  bf16 MxD    [0,16M)
    //   Vb  bf16 MxD    [16M,32M)
    //   H   bf16 Mx2D   [32M,64M)   -- xb overlays H's first 16 MB (dead before H written)
    unsigned short* Ub = (unsigned short*)d_ws;
    unsigned short* Vb = Ub + (size_t)M * 256;
    unsigned short* H  = Vb + (size_t)M * 256;
    unsigned short* xb = H;
    unsigned short* W2 = H + (size_t)M * 512;        // 512x256 bf16
    unsigned short* W3 = W2 + (size_t)512 * 256;     // 256x512 bf16
    float* cre = (float*)(W3 + (size_t)256 * 512);   // 8*64*256 f32
    float* cim = cre + (size_t)NBATCH * NC * 256;
    float* Lr  = cim + (size_t)NBATCH * NC * 256;
    float* Li  = Lr + 256;

    prep_params<<<1, 256, 0, stream>>>(nu_log, theta_log, Lr, Li);
    prep_w<<<768, 256, 0, stream>>>(B_re, B_im, gamma_log, C_re, C_im, W2, W3);
    conv_x<<<(M * 256) / 2048, 256, 0, stream>>>(x, xb);
    gemm_bt<256, 0><<<dim3(M / 128, 4), 256, 0, stream>>>(xb, W2, Ub, Vb, nullptr);
    scan_ends<<<NBATCH * NC, 256, 0, stream>>>(Ub, Vb, Lr, Li, cre, cim);
    scan_carry<<<NBATCH, 256, 0, stream>>>(cre, cim, Lr, Li);
    scan_apply<<<NBATCH * NC, 256, 0, stream>>>(Ub, Vb, Lr, Li, cre, cim, H);
    gemm_bt<512, 1><<<dim3(M / 128, 2), 256, 0, stream>>>(H, W3, nullptr, nullptr, out);
}

// Round 5
// 79.240 us; speedup vs baseline: 3.9060x; 1.0289x over previous
//
#include <hip/hip_runtime.h>
#include <math.h>

#define D 256
#define NBATCH 8
#define T 4096
#define M (NBATCH * T)     // 32768
#define LC 64              // chunk length
#define NC (T / LC)        // 64 chunks

typedef __attribute__((ext_vector_type(8))) short bf16x8;
typedef __attribute__((ext_vector_type(4))) float f32x4;

__device__ __forceinline__ unsigned short f2bf(float f) {
    unsigned int u = __float_as_uint(f);
    u += 0x7fff + ((u >> 16) & 1);          // RNE
    return (unsigned short)(u >> 16);
}
__device__ __forceinline__ float bf2f(unsigned short s) {
    return __uint_as_float(((unsigned int)s) << 16);
}

__device__ __forceinline__ void gl_lds16(const unsigned short* g, unsigned short* l) {
    __builtin_amdgcn_global_load_lds(
        (const __attribute__((address_space(1))) unsigned int*)g,
        (__attribute__((address_space(3))) unsigned int*)l, 16, 0, 0);
}

// ---------------- params: L diagonal ----------------
__global__ void prep_params(const float* __restrict__ nu_log,
                            const float* __restrict__ theta_log,
                            float* __restrict__ Lr, float* __restrict__ Li) {
    int d = threadIdx.x;
    float lmod = expf(-expf(nu_log[d]));
    float th = expf(theta_log[d]);
    Lr[d] = lmod * cosf(th);
    Li[d] = lmod * sinf(th);
}

// ---------------- weights: W2 = [Bre*g ; Bim*g] (512x256), W3 = [Cre | -Cim] (256x512)
__global__ __launch_bounds__(256) void prep_w(const float* __restrict__ Bre,
                                              const float* __restrict__ Bim,
                                              const float* __restrict__ gamma_log,
                                              const float* __restrict__ Cre,
                                              const float* __restrict__ Cim,
                                              unsigned short* __restrict__ W2,
                                              unsigned short* __restrict__ W3) {
    int n = blockIdx.x, k = threadIdx.x;
    if (n < 512) {
        int r = n & 255;
        float g = expf(gamma_log[r]);
        const float* src = (n < 256) ? Bre : Bim;
        W2[(size_t)n * 256 + k] = f2bf(src[(size_t)r * 256 + k] * g);
    } else {
        int r = n - 512;
        W3[(size_t)r * 512 + k]       = f2bf(Cre[(size_t)r * 256 + k]);
        W3[(size_t)r * 512 + 256 + k] = f2bf(-Cim[(size_t)r * 256 + k]);
    }
}

// ---------------- proj GEMM: A = x (fp32, converted in staging), W = W2 (bf16, B^T)
// 128x128 tile, BK=32, 4 waves, 16x16x32 mfma. Cols 0-255 -> Ub, 256-511 -> Vb.
__global__ __launch_bounds__(256) void proj_gemm(const float* __restrict__ x,
                                                 const unsigned short* __restrict__ W,
                                                 unsigned short* __restrict__ oU,
                                                 unsigned short* __restrict__ oV) {
    __shared__ __align__(16) unsigned short As[128 * 32];
    __shared__ __align__(16) unsigned short Bs[128 * 32];
    const int tid  = threadIdx.x;
    const int lane = tid & 63;
    const int wid  = tid >> 6;
    const int m0 = blockIdx.x * 128;
    const int n0 = blockIdx.y * 128;
    const int wr = wid >> 1, wc = wid & 1;

    f32x4 acc[4][4];
#pragma unroll
    for (int i = 0; i < 4; ++i)
#pragma unroll
        for (int j = 0; j < 4; ++j) acc[i][j] = (f32x4){0.f, 0.f, 0.f, 0.f};

    // A staging (regs, fp32->bf16): thread covers rows arow+32i, col quad aq
    const int aq = tid & 7, arow = tid >> 3;
    const float* gx = x + (size_t)(m0 + arow) * 256 + aq * 4;
    unsigned short* lA = As + arow * 32 + aq * 4;
    // B staging via global_load_lds (verified round-2 mapping)
    const int sr = lane >> 2, sc = (lane & 3) * 8;
    const unsigned short* gW0 = W + (size_t)(n0 + wid * 32 + sr) * 256 + sc;
    const unsigned short* gW1 = gW0 + (size_t)16 * 256;
    unsigned short* lB0 = Bs + wid * 1024;
    unsigned short* lB1 = lB0 + 512;

    const int ar = lane & 15;
    const int ak = (lane >> 4) * 8;

    for (int k0 = 0; k0 < 256; k0 += 32) {
        gl_lds16(gW0 + k0, lB0);
        gl_lds16(gW1 + k0, lB1);
#pragma unroll
        for (int i = 0; i < 4; ++i) {
            float4 v = *(const float4*)(gx + (size_t)(32 * i) * 256 + k0);
            union { ushort4 s; unsigned long long u; } o;
            o.s.x = f2bf(v.x); o.s.y = f2bf(v.y); o.s.z = f2bf(v.z); o.s.w = f2bf(v.w);
            *(unsigned long long*)(lA + (size_t)i * 32 * 32) = o.u;
        }
        __syncthreads();
        bf16x8 a[4], b[4];
#pragma unroll
        for (int mi = 0; mi < 4; ++mi)
            a[mi] = *(const bf16x8*)(As + (wr * 64 + mi * 16 + ar) * 32 + ak);
#pragma unroll
        for (int ni = 0; ni < 4; ++ni)
            b[ni] = *(const bf16x8*)(Bs + (wc * 64 + ni * 16 + ar) * 32 + ak);
#pragma unroll
        for (int mi = 0; mi < 4; ++mi)
#pragma unroll
            for (int ni = 0; ni < 4; ++ni)
                acc[mi][ni] = __builtin_amdgcn_mfma_f32_16x16x32_bf16(a[mi], b[ni], acc[mi][ni], 0, 0, 0);
        __syncthreads();
    }

    // C/D layout (16x16x32): col = lane&15, row = (lane>>4)*4 + j
    const int crow = (lane >> 4) * 4;
    const int ccol = lane & 15;
    unsigned short* base = (n0 < 256) ? oU : oV;
    const int nb = (n0 < 256) ? n0 : (n0 - 256);
#pragma unroll
    for (int mi = 0; mi < 4; ++mi)
#pragma unroll
        for (int ni = 0; ni < 4; ++ni) {
            const int r = m0 + wr * 64 + mi * 16 + crow;
            const int c = nb + wc * 64 + ni * 16 + ccol;
#pragma unroll
            for (int j = 0; j < 4; ++j)
                base[(size_t)(r + j) * 256 + c] = f2bf(acc[mi][ni][j]);
        }
}

// ---------------- out GEMM: A = H (bf16), W = W3 (bf16, B^T), fp32 out
__global__ __launch_bounds__(256) void out_gemm(const unsigned short* __restrict__ A,
                                                const unsigned short* __restrict__ W,
                                                float* __restrict__ oF) {
    __shared__ __align__(16) unsigned short As[128 * 32];
    __shared__ __align__(16) unsigned short Bs[128 * 32];
    const int tid  = threadIdx.x;
    const int lane = tid & 63;
    const int wid  = tid >> 6;
    const int m0 = blockIdx.x * 128;
    const int n0 = blockIdx.y * 128;
    const int wr = wid >> 1, wc = wid & 1;

    f32x4 acc[4][4];
#pragma unroll
    for (int i = 0; i < 4; ++i)
#pragma unroll
        for (int j = 0; j < 4; ++j) acc[i][j] = (f32x4){0.f, 0.f, 0.f, 0.f};

    const int sr = lane >> 2;
    const int sc = (lane & 3) * 8;
    const unsigned short* gA0 = A + (size_t)(m0 + wid * 32 + sr) * 512 + sc;
    const unsigned short* gA1 = gA0 + (size_t)16 * 512;
    const unsigned short* gW0 = W + (size_t)(n0 + wid * 32 + sr) * 512 + sc;
    const unsigned short* gW1 = gW0 + (size_t)16 * 512;
    unsigned short* lA0 = As + wid * 1024;
    unsigned short* lA1 = lA0 + 512;
    unsigned short* lB0 = Bs + wid * 1024;
    unsigned short* lB1 = lB0 + 512;

    const int ar = lane & 15;
    const int ak = (lane >> 4) * 8;

    for (int k0 = 0; k0 < 512; k0 += 32) {
        gl_lds16(gA0 + k0, lA0);
        gl_lds16(gA1 + k0, lA1);
        gl_lds16(gW0 + k0, lB0);
        gl_lds16(gW1 + k0, lB1);
        __syncthreads();
        bf16x8 a[4], b[4];
#pragma unroll
        for (int mi = 0; mi < 4; ++mi)
            a[mi] = *(const bf16x8*)(As + (wr * 64 + mi * 16 + ar) * 32 + ak);
#pragma unroll
        for (int ni = 0; ni < 4; ++ni)
            b[ni] = *(const bf16x8*)(Bs + (wc * 64 + ni * 16 + ar) * 32 + ak);
#pragma unroll
        for (int mi = 0; mi < 4; ++mi)
#pragma unroll
            for (int ni = 0; ni < 4; ++ni)
                acc[mi][ni] = __builtin_amdgcn_mfma_f32_16x16x32_bf16(a[mi], b[ni], acc[mi][ni], 0, 0, 0);
        __syncthreads();
    }

    const int crow = (lane >> 4) * 4;
    const int ccol = lane & 15;
#pragma unroll
    for (int mi = 0; mi < 4; ++mi)
#pragma unroll
        for (int ni = 0; ni < 4; ++ni) {
            const int r = m0 + wr * 64 + mi * 16 + crow;
            const int c = n0 + wc * 64 + ni * 16 + ccol;
#pragma unroll
            for (int j = 0; j < 4; ++j)
                oF[(size_t)(r + j) * 256 + c] = acc[mi][ni][j];
        }
}

// ---------------- scan pass A: chunk-local end states (read-only)
__global__ __launch_bounds__(256) void scan_ends(const unsigned short* __restrict__ Ub,
                                                 const unsigned short* __restrict__ Vb,
                                                 const float* __restrict__ Lr,
                                                 const float* __restrict__ Li,
                                                 float* __restrict__ cre, float* __restrict__ cim) {
    int d = threadIdx.x;
    int bc = blockIdx.x;
    float lr = Lr[d], li = Li[d];
    float hr = 0.f, hi = 0.f;
    size_t base = (size_t)bc * LC * 256 + d;
    for (int t = 0; t < LC; t++) {
        float u = bf2f(Ub[base + (size_t)t * 256]);
        float v = bf2f(Vb[base + (size_t)t * 256]);
        float nr = fmaf(lr, hr, fmaf(-li, hi, u));
        float ni = fmaf(lr, hi, fmaf(li, hr, v));
        hr = nr; hi = ni;
    }
    cre[(size_t)bc * 256 + d] = hr;
    cim[(size_t)bc * 256 + d] = hi;
}

// ---------------- scan pass B: carries across chunks (exclusive), A = L^LC
__global__ __launch_bounds__(256) void scan_carry(float* __restrict__ cre, float* __restrict__ cim,
                                                  const float* __restrict__ Lr,
                                                  const float* __restrict__ Li) {
    int d = threadIdx.x;
    int b = blockIdx.x;
    float lr = Lr[d], li = Li[d];
    float ar = 1.f, ai = 0.f;
    for (int i = 0; i < LC; i++) {
        float nr = ar * lr - ai * li;
        float ni = ar * li + ai * lr;
        ar = nr; ai = ni;
    }
    float hr = 0.f, hi = 0.f;
    for (int c = 0; c < NC; c++) {
        size_t idx = ((size_t)b * NC + c) * 256 + d;
        float xr = cre[idx], xi = cim[idx];
        cre[idx] = hr;
        cim[idx] = hi;
        float nr = fmaf(ar, hr, fmaf(-ai, hi, xr));
        float ni = fmaf(ar, hi, fmaf(ai, hr, xi));
        hr = nr; hi = ni;
    }
}

// ---------------- scan pass C: full scan with carry-in, emit H = [hr | hi] bf16 (M x 512)
__global__ __launch_bounds__(256) void scan_apply(const unsigned short* __restrict__ Ub,
                                                  const unsigned short* __restrict__ Vb,
                                                  const float* __restrict__ Lr,
                                                  const float* __restrict__ Li,
                                                  const float* __restrict__ cre,
                                                  const float* __restrict__ cim,
                                                  unsigned short* __restrict__ H) {
    int d = threadIdx.x;
    int bc = blockIdx.x;
    float lr = Lr[d], li = Li[d];
    float hr = cre[(size_t)bc * 256 + d];
    float hi = cim[(size_t)bc * 256 + d];
    size_t base  = (size_t)bc * LC * 256 + d;
    size_t hbase = (size_t)bc * LC * 512 + d;
    for (int t = 0; t < LC; t++) {
        float u = bf2f(Ub[base + (size_t)t * 256]);
        float v = bf2f(Vb[base + (size_t)t * 256]);
        float nr = fmaf(lr, hr, fmaf(-li, hi, u));
        float ni = fmaf(lr, hi, fmaf(li, hr, v));
        hr = nr; hi = ni;
        H[hbase + (size_t)t * 512]       = f2bf(hr);
        H[hbase + (size_t)t * 512 + 256] = f2bf(hi);
    }
}

extern "C" void kernel_launch(void* const* d_in, const int* in_sizes, int n_in,
                              void* d_out, int out_size, void* d_ws, size_t ws_size,
                              hipStream_t stream) {
    const float* x         = (const float*)d_in[0];
    const float* nu_log    = (const float*)d_in[1];
    const float* theta_log = (const float*)d_in[2];
    const float* gamma_log = (const float*)d_in[3];
    const float* B_re      = (const float*)d_in[4];
    const float* B_im      = (const float*)d_in[5];
    const float* C_re      = (const float*)d_in[6];
    const float* C_im      = (const float*)d_in[7];
    float* out = (float*)d_out;

    unsigned short* Ub = (unsigned short*)d_ws;          // M*256 bf16 (16 MB)
    unsigned short* Vb = Ub + (size_t)M * 256;           // 16 MB
    unsigned short* H  = Vb + (size_t)M * 256;           // M*512 bf16 (32 MB)
    unsigned short* W2 = H + (size_t)M * 512;            // 512x256 bf16
    unsigned short* W3 = W2 + (size_t)512 * 256;         // 256x512 bf16
    float* cre = (float*)(W3 + (size_t)256 * 512);       // 8*64*256 f32
    float* cim = cre + (size_t)NBATCH * NC * 256;
    float* Lr  = cim + (size_t)NBATCH * NC * 256;
    float* Li  = Lr + 256;

    prep_params<<<1, 256, 0, stream>>>(nu_log, theta_log, Lr, Li);
    prep_w<<<768, 256, 0, stream>>>(B_re, B_im, gamma_log, C_re, C_im, W2, W3);
    proj_gemm<<<dim3(M / 128, 4), 256, 0, stream>>>(x, W2, Ub, Vb);
    scan_ends<<<NBATCH * NC, 256, 0, stream>>>(Ub, Vb, Lr, Li, cre, cim);
    scan_carry<<<NBATCH, 256, 0, stream>>>(cre, cim, Lr, Li);
    scan_apply<<<NBATCH * NC, 256, 0, stream>>>(Ub, Vb, Lr, Li, cre, cim, H);
    out_gemm<<<dim3(M / 128, 2), 256, 0, stream>>>(H, W3, out);
}